// Round 9
// baseline (347.588 us; speedup 1.0000x reference)
//
#include <hip/hip_runtime.h>
#include <hip/hip_bf16.h>

// B=8, N=2048, Q=256, D=1024, H=16, HD=64 cross-attention.
// R15 = R14 with the P-rearrange shuffle FIXED. R14's bug: `sel ? u10 : u00`
// before __shfl selects with the SOURCE lane's sel (= dest's kq&1), not the
// dest's needed mi (= kq>>1) -> keys 8-15 / 16-23 swapped for half the lanes
// (absmax 0.203). Fix: shuffle both u0x and u1x, select AFTER on the dest
// side (8 bpermute + 4 cndmask per tile). Also: l accumulates the
// bf16-ROUNDED P values (unpacked from the cvt_pk words) so the denominator
// matches the numerator's rounding, as in R11's ones-MFMA.
// attn: barrier-free, LDS-free; each wave owns 16 q, sweeps 2048 keys in
// 32-key tiles; K/V/Q per-lane direct global loads (L1/L2-served, XCD-chunked).
// kv8 / proj_q / casts / out-proj byte-identical to R14.

typedef unsigned short u16;
typedef __attribute__((ext_vector_type(8))) short short8;   // 8 bf16 = 4 VGPR
typedef __attribute__((ext_vector_type(4))) float floatx4;  // MFMA acc
typedef __attribute__((ext_vector_type(4))) int intx4;

static_assert(sizeof(short8) == 16, "short8 must be 16B");

__device__ __forceinline__ u16 f2bf(float f) {
  unsigned int x = __float_as_uint(f);
  x += 0x7fffu + ((x >> 16) & 1u);   // RNE
  return (u16)(x >> 16);
}

// pack 2 f32 -> 2 bf16 (RNE) in one instruction; elem0 = lo
__device__ __forceinline__ unsigned int cvtpk(float lo, float hi) {
  unsigned int r;
  asm("v_cvt_pk_bf16_f32 %0, %1, %2" : "=v"(r) : "v"(lo), "v"(hi));
  return r;
}

// async global->LDS, 16 B per lane; lds = wave-uniform base, lane i -> base+i*16
__device__ __forceinline__ void gload16(const u16* g, u16* lds) {
  __builtin_amdgcn_global_load_lds(
      (const __attribute__((address_space(1))) unsigned int*)g,
      (__attribute__((address_space(3))) unsigned int*)lds, 16, 0, 0);
}

template <int N> __device__ __forceinline__ void vmwait() {
  if constexpr (N == 0)      asm volatile("s_waitcnt vmcnt(0)" ::: "memory");
  else if constexpr (N == 4) asm volatile("s_waitcnt vmcnt(4)" ::: "memory");
  else if constexpr (N == 6) asm volatile("s_waitcnt vmcnt(6)" ::: "memory");
  else if constexpr (N == 8) asm volatile("s_waitcnt vmcnt(8)" ::: "memory");
  else static_assert(N == 0, "unsupported vmcnt immediate");
}

__device__ __forceinline__ void lgkm0() {
  asm volatile("s_waitcnt lgkmcnt(0)" ::: "memory");
}

__device__ __forceinline__ void sfence() { __builtin_amdgcn_sched_barrier(0); }

// ---------------- single fused fp32 -> bf16 cast over all 4 inputs ----------------
__global__ __launch_bounds__(256) void f2bf_multi(
    const float* __restrict__ s, u16* __restrict__ so,
    const float* __restrict__ q, u16* __restrict__ qo,
    const float* __restrict__ wi, u16* __restrict__ wio,
    const float* __restrict__ wo, u16* __restrict__ woo) {
  int i = blockIdx.x * 256 + threadIdx.x;
  const float* in; u16* out; int idx;
  if (i < 4194304)      { in = s;  out = so;  idx = i; }
  else if (i < 4718592) { in = q;  out = qo;  idx = i - 4194304; }
  else if (i < 5505024) { in = wi; out = wio; idx = i - 4718592; }
  else if (i < 5767168) { in = wo; out = woo; idx = i - 5505024; }
  else return;
  float4 v = reinterpret_cast<const float4*>(in)[idx];
  ushort4 o;
  o.x = f2bf(v.x); o.y = f2bf(v.y); o.z = f2bf(v.z); o.w = f2bf(v.w);
  reinterpret_cast<ushort4*>(out)[idx] = o;
}

// ---------------- 2-phase pipelined GEMM core: tile (MT*32)x(NT*32), BK=64 ----
template <int MT, int NT>
__device__ __forceinline__ void gemm_core(
    const u16* __restrict__ A, int lda,
    const u16* __restrict__ Bm, int ldb, int K,
    u16* __restrict__ Alds, u16* __restrict__ Blds,
    floatx4 (&acc)[MT][NT]) {
  const int t = threadIdx.x;
  const int wave = t >> 6, lane = t & 63;
  const int rr = lane & 15, kq = lane >> 4;
  constexpr int AI = MT, BI = NT;
  constexpr int AELEMS = MT * 32 * 64;
  constexpr int BELEMS = NT * 32 * 64;

  const u16* ag[AI]; u16* al[AI];
#pragma unroll
  for (int i = 0; i < AI; ++i) {
    int s = i * 256 + t;
    int row = s >> 3, c16 = s & 7;
    ag[i] = A + (size_t)row * lda + ((c16 ^ (row & 7)) * 8);
    al[i] = Alds + (size_t)(i * 256 + wave * 64) * 8;
  }
  const u16* bg[BI]; u16* blp[BI];
#pragma unroll
  for (int i = 0; i < BI; ++i) {
    int s = i * 256 + t;
    int row = s >> 3, c16 = s & 7;
    bg[i] = Bm + (size_t)row * ldb + ((c16 ^ (row & 7)) * 8);
    blp[i] = Blds + (size_t)(i * 256 + wave * 64) * 8;
  }

  const int m0w = (wave & 1) * (MT * 16);
  const int n0w = (wave >> 1) * (NT * 16);
  int aoff[MT][2], boff[NT][2];
#pragma unroll
  for (int mi = 0; mi < MT; ++mi) {
    int row = m0w + mi * 16 + rr;
#pragma unroll
    for (int kk = 0; kk < 2; ++kk)
      aoff[mi][kk] = row * 64 + (((kk * 4 + kq) ^ (row & 7)) * 8);
  }
#pragma unroll
  for (int ni = 0; ni < NT; ++ni) {
    int row = n0w + ni * 16 + rr;
#pragma unroll
    for (int kk = 0; kk < 2; ++kk)
      boff[ni][kk] = row * 64 + (((kk * 4 + kq) ^ (row & 7)) * 8);
  }

  auto compute = [&](int bs) {
    const u16* Ab = Alds + bs * AELEMS;
    const u16* Bb = Blds + bs * BELEMS;
#pragma unroll
    for (int kk = 0; kk < 2; ++kk) {
      short8 af[MT], bfr[NT];
#pragma unroll
      for (int mi = 0; mi < MT; ++mi)
        af[mi] = *reinterpret_cast<const short8*>(Ab + aoff[mi][kk]);
#pragma unroll
      for (int ni = 0; ni < NT; ++ni)
        bfr[ni] = *reinterpret_cast<const short8*>(Bb + boff[ni][kk]);
      __builtin_amdgcn_s_setprio(1);
#pragma unroll
      for (int mi = 0; mi < MT; ++mi)
#pragma unroll
        for (int ni = 0; ni < NT; ++ni)
          acc[mi][ni] = __builtin_amdgcn_mfma_f32_16x16x32_bf16(af[mi], bfr[ni], acc[mi][ni], 0, 0, 0);
      __builtin_amdgcn_s_setprio(0);
    }
  };

  const int nt = K >> 6;

#pragma unroll
  for (int i = 0; i < AI; ++i) gload16(ag[i], al[i]);
#pragma unroll
  for (int i = 0; i < BI; ++i) gload16(bg[i], blp[i]);

  int cur = 0;
#pragma unroll 1
  for (int tt = 0; tt < nt - 1; ++tt) {
    const int nxt = cur ^ 1;
    const int koff = (tt + 1) * 64;
#pragma unroll
    for (int i = 0; i < AI; ++i) gload16(ag[i] + koff, al[i] + nxt * AELEMS);
#pragma unroll
    for (int i = 0; i < BI; ++i) gload16(bg[i] + koff, blp[i] + nxt * BELEMS);
    sfence();
    vmwait<AI + BI>();
    __builtin_amdgcn_s_barrier();
    sfence();
    compute(cur);
    sfence();
    __builtin_amdgcn_s_barrier();
    cur = nxt;
  }
  sfence();
  vmwait<0>();
  __builtin_amdgcn_s_barrier();
  sfence();
  compute(cur);
}

// ================= 8-phase 256x256 K/V projection (R8/R11) =================
template <int LO>
__device__ __forceinline__ void read_a8(const u16* ab, int kcol0, int kcol1,
                                        short8 (&af)[8][2]) {
#pragma unroll
  for (int mi = 0; mi < 4; ++mi) {
    af[LO + mi][0] = *reinterpret_cast<const short8*>(ab + (LO + mi) * 1024 + kcol0);
    af[LO + mi][1] = *reinterpret_cast<const short8*>(ab + (LO + mi) * 1024 + kcol1);
  }
}

template <int LO>
__device__ __forceinline__ void read_b8(const u16* bb, int kcol0, int kcol1,
                                        short8 (&bf)[4][2]) {
#pragma unroll
  for (int ni = 0; ni < 2; ++ni) {
    bf[LO + ni][0] = *reinterpret_cast<const short8*>(bb + (LO + ni) * 1024 + kcol0);
    bf[LO + ni][1] = *reinterpret_cast<const short8*>(bb + (LO + ni) * 1024 + kcol1);
  }
}

template <int M0, int N0>
__device__ __forceinline__ void quad8(const short8 (&af)[8][2], const short8 (&bf)[4][2],
                                      floatx4 (&acc)[8][4]) {
  __builtin_amdgcn_s_setprio(1);
#pragma unroll
  for (int kk = 0; kk < 2; ++kk)
#pragma unroll
    for (int mi = 0; mi < 4; ++mi)
#pragma unroll
      for (int ni = 0; ni < 2; ++ni)
        acc[M0 + mi][N0 + ni] = __builtin_amdgcn_mfma_f32_16x16x32_bf16(
            af[M0 + mi][kk], bf[N0 + ni][kk], acc[M0 + mi][N0 + ni], 0, 0, 0);
  __builtin_amdgcn_s_setprio(0);
}

__global__ __launch_bounds__(512, 2) void gemm_proj_kv8(
    const u16* __restrict__ s_bf, const u16* __restrict__ wi_bf,
    const float* __restrict__ b_in,
    u16* __restrict__ kp, u16* __restrict__ vT) {
  __shared__ __attribute__((aligned(16))) u16 Alds[2 * 256 * 64];  // 64 KiB
  __shared__ __attribute__((aligned(16))) u16 Blds[2 * 256 * 64];  // 64 KiB

  int bid = blockIdx.y * 8 + blockIdx.x;
  int nb = (bid & 7) * 64 + (bid >> 3);
  const int by = nb >> 3, bx = nb & 7;
  const int mB = by * 256;
  const int nB = bx * 256;
  const u16* Ag = s_bf + (size_t)mB * 1024;
  const u16* Wg = wi_bf + (size_t)(1024 + nB) * 1024;
  const float* bias = b_in + 1024 + nB;

  const int t = threadIdx.x;
  const int w = t >> 6, lane = t & 63;
  const int rr = lane & 15, kq = lane >> 4;
  const int wr = w >> 2, wc = w & 3;

  const u16* ga[2][2]; const u16* gb[2][2];
#pragma unroll
  for (int h = 0; h < 2; ++h)
#pragma unroll
    for (int i = 0; i < 2; ++i) {
      int s = i * 512 + t;
      int row = h * 128 + (s >> 3), c16 = s & 7;
      ga[h][i] = Ag + (size_t)row * 1024 + ((c16 ^ (row & 7)) * 8);
      gb[h][i] = Wg + (size_t)row * 1024 + ((c16 ^ (row & 7)) * 8);
    }

#define STAGE_A8(j, h) { const int d_ = ((j) & 1) * 16384;                         \
    gload16(ga[h][0] + (size_t)(j) * 64, Alds + d_ + (h) * 8192 + w * 512);        \
    gload16(ga[h][1] + (size_t)(j) * 64, Alds + d_ + (h) * 8192 + 4096 + w * 512); }
#define STAGE_B8(j, h) { const int d_ = ((j) & 1) * 16384;                         \
    gload16(gb[h][0] + (size_t)(j) * 64, Blds + d_ + (h) * 8192 + w * 512);        \
    gload16(gb[h][1] + (size_t)(j) * 64, Blds + d_ + (h) * 8192 + 4096 + w * 512); }

  const int kcol0 = ((kq) ^ (rr & 7)) * 8;
  const int kcol1 = ((4 + kq) ^ (rr & 7)) * 8;
  const u16* abase = Alds + (wr * 128 + rr) * 64;
  const u16* bbase = Blds + (wc * 64 + rr) * 64;

  short8 af[8][2], bf[4][2];
  const floatx4 zz = {0.f, 0.f, 0.f, 0.f};
  floatx4 acc[8][4];
#pragma unroll
  for (int mi = 0; mi < 8; ++mi)
#pragma unroll
    for (int ni = 0; ni < 4; ++ni) acc[mi][ni] = zz;

  STAGE_A8(0, 0); STAGE_B8(0, 0); STAGE_A8(0, 1); STAGE_B8(0, 1);
  STAGE_A8(1, 0); STAGE_B8(1, 0);
  sfence();
  vmwait<4>();
  __builtin_amdgcn_s_barrier();
  sfence();

#pragma unroll 1
  for (int kt = 0; kt < 16; ++kt) {
    const int doff = (kt & 1) * 16384;
    const u16* ab = abase + doff;
    const u16* bb = bbase + doff;
    read_a8<0>(ab, kcol0, kcol1, af);
    read_b8<0>(bb, kcol0, kcol1, bf);
    if (kt + 1 < 16) STAGE_A8(kt + 1, 1);
    sfence();
    __builtin_amdgcn_s_barrier();
    lgkm0(); sfence();
    quad8<0, 0>(af, bf, acc);
    sfence();
    __builtin_amdgcn_s_barrier();
    sfence();
    read_a8<4>(ab, kcol0, kcol1, af);
    read_b8<2>(bb, kcol0, kcol1, bf);
    if (kt + 1 < 16) STAGE_B8(kt + 1, 1);
    sfence();
    __builtin_amdgcn_s_barrier();
    lgkm0(); sfence();
    quad8<0, 2>(af, bf, acc);
    sfence();
    __builtin_amdgcn_s_barrier();
    sfence();
    if (kt + 2 < 16) STAGE_A8(kt + 2, 0);
    sfence();
    __builtin_amdgcn_s_barrier();
    quad8<4, 0>(af, bf, acc);
    sfence();
    __builtin_amdgcn_s_barrier();
    sfence();
    if (kt + 2 < 16) { STAGE_B8(kt + 2, 0); sfence(); vmwait<4>(); }
    else             { sfence(); vmwait<0>(); }
    __builtin_amdgcn_s_barrier();
    quad8<4, 2>(af, bf, acc);
    sfence();
    __builtin_amdgcn_s_barrier();
    sfence();
  }
#undef STAGE_A8
#undef STAGE_B8

  const int r4 = kq * 4;
  const int m0w = wr * 128, n0w = wc * 64;
  if (nB < 1024) {
#pragma unroll
    for (int mi = 0; mi < 8; ++mi)
#pragma unroll
      for (int ni = 0; ni < 4; ++ni) {
        int nl = n0w + ni * 16 + rr;
        float bv = bias[nl];
#pragma unroll
        for (int r = 0; r < 4; ++r) {
          int m = mB + m0w + mi * 16 + r4 + r;
          kp[(size_t)m * 1024 + nB + nl] = f2bf(acc[mi][ni][r] + bv);
        }
      }
  } else {
#pragma unroll
    for (int mi = 0; mi < 8; ++mi)
#pragma unroll
      for (int ni = 0; ni < 4; ++ni) {
        int n2 = nB + n0w + ni * 16 + rr - 1024;
        int h = n2 >> 6, d = n2 & 63;
        float bv = bias[n0w + ni * 16 + rr];
        int m0 = mB + m0w + mi * 16 + r4;
        int b = m0 >> 11, j0 = m0 & 2047;
        ushort4 o;
        o.x = f2bf(acc[mi][ni][0] + bv);
        o.y = f2bf(acc[mi][ni][1] + bv);
        o.z = f2bf(acc[mi][ni][2] + bv);
        o.w = f2bf(acc[mi][ni][3] + bv);
        *reinterpret_cast<ushort4*>(
            vT + ((size_t)(b * 16 + h) * 64 + d) * 2048 + j0) = o;
      }
  }
}

// ---- Q projection: small (3% of proj FLOPs), 128^2 2-phase core ----
__global__ __launch_bounds__(256, 2) void gemm_proj_q(
    const u16* __restrict__ qy_bf, const u16* __restrict__ wi_bf,
    const float* __restrict__ b_in, u16* __restrict__ qp) {
  __shared__ __attribute__((aligned(16))) u16 Alds[2 * 128 * 64];
  __shared__ __attribute__((aligned(16))) u16 Blds[2 * 128 * 64];
  const int mB = blockIdx.y * 128;
  const int nB = blockIdx.x * 128;
  const u16* A = qy_bf + (size_t)mB * 1024;
  const u16* W = wi_bf + (size_t)nB * 1024;
  const float* bias = b_in + nB;

  const floatx4 zz = {0.f, 0.f, 0.f, 0.f};
  floatx4 acc[4][4] = {{zz, zz, zz, zz}, {zz, zz, zz, zz}, {zz, zz, zz, zz}, {zz, zz, zz, zz}};
  gemm_core<4, 4>(A, 1024, W, 1024, 1024, Alds, Blds, acc);

  const int lane = threadIdx.x & 63, wave = threadIdx.x >> 6;
  const int rr = lane & 15, r4 = (lane >> 4) * 4;
  const int m0w = (wave & 1) * 64, n0w = (wave >> 1) * 64;
#pragma unroll
  for (int mi = 0; mi < 4; ++mi)
#pragma unroll
    for (int ni = 0; ni < 4; ++ni) {
      int nl = n0w + ni * 16 + rr;
      float bv = bias[nl];
#pragma unroll
      for (int r = 0; r < 4; ++r) {
        int m = mB + m0w + mi * 16 + r4 + r;
        qp[(size_t)m * 1024 + nB + nl] = f2bf((acc[mi][ni][r] + bv) * 0.125f);
      }
    }
}

// ================= fused attention R15: barrier-free, LDS-free (fixed) =========
// 512 blocks = (b,h,qquad); 4 waves/block, each wave owns 16 q independently.
// S^T = mfma(K,Q): lane (rr,kq) holds P[q=rr][keys mi*16+kq*4+r].
// PV A-frag: lane (rr,kq) needs P[q=rr][keys kq*8..+7]; word w comes from lane
// sb+16*(w>>1) (sb = rr+32*(kq&1)), value u[mi=kq>>1][w&1]. mi is the DEST's
// half -> shuffle BOTH u0x and u1x, select after (8 bpermute + 4 cndmask).
__global__ __launch_bounds__(256, 4) void attn_fused(
    const u16* __restrict__ qp, const u16* __restrict__ kp,
    const u16* __restrict__ vT, u16* __restrict__ ao) {
  const int bid = blockIdx.x;
  const int nb = (bid & 7) * 64 + (bid >> 3);   // XCD-chunked
  const int bh = nb >> 2, qq = nb & 3;
  const int b = bh >> 4, h = bh & 15;

  const int t = threadIdx.x;
  const int w = t >> 6, lane = t & 63;
  const int rr = lane & 15, kq = lane >> 4;
  const int q0 = qq * 64 + w * 16;              // wave's q base in [0,256)

  // Q fragment (B-operand): lane(rr,kq): q = q0+rr, k(d) = kc*32 + kq*8
  const u16* qrow = qp + ((size_t)(b * 256 + q0 + rr)) * 1024 + h * 64 + kq * 8;
  short8 qf[2];
  qf[0] = *reinterpret_cast<const short8*>(qrow);
  qf[1] = *reinterpret_cast<const short8*>(qrow + 32);

  // K fragment base (A-operand): key = kt*32 + mi*16 + rr, d = kc*32 + kq*8
  const u16* kbase = kp + ((size_t)(b * 2048 + rr)) * 1024 + h * 64 + kq * 8;
  // V fragment base (B-operand): d = ni*16 + rr, k(key) = kt*32 + kq*8
  const u16* vbase = vT + ((size_t)(bh * 64 + rr)) * 2048 + kq * 8;

  const floatx4 zz = {0.f, 0.f, 0.f, 0.f};
  floatx4 oacc[4] = {zz, zz, zz, zz};
  float l_acc = 0.f;

  const int sel = kq >> 1;                  // DEST's mi half
  const int sb = rr + ((kq & 1) << 5);      // src lane base

#pragma unroll 1
  for (int kt = 0; kt < 64; ++kt) {
    // ---- loads (compiler-managed waitcnts; TLP hides latency)
    const u16* kp0 = kbase + (size_t)(kt * 32) * 1024;
    short8 kf0 = *reinterpret_cast<const short8*>(kp0);
    short8 kf1 = *reinterpret_cast<const short8*>(kp0 + 32);
    short8 kf2 = *reinterpret_cast<const short8*>(kp0 + 16 * 1024);
    short8 kf3 = *reinterpret_cast<const short8*>(kp0 + 16 * 1024 + 32);
    const u16* vp0 = vbase + kt * 32;
    short8 vf0 = *reinterpret_cast<const short8*>(vp0);
    short8 vf1 = *reinterpret_cast<const short8*>(vp0 + 16 * 2048);
    short8 vf2 = *reinterpret_cast<const short8*>(vp0 + 32 * 2048);
    short8 vf3 = *reinterpret_cast<const short8*>(vp0 + 48 * 2048);

    // ---- S^T = K.Q : sacc[mi][r] = S[key=mi*16+kq*4+r][q=rr]
    floatx4 sacc0 = zz, sacc1 = zz;
    sacc0 = __builtin_amdgcn_mfma_f32_16x16x32_bf16(kf0, qf[0], sacc0, 0, 0, 0);
    sacc0 = __builtin_amdgcn_mfma_f32_16x16x32_bf16(kf1, qf[1], sacc0, 0, 0, 0);
    sacc1 = __builtin_amdgcn_mfma_f32_16x16x32_bf16(kf2, qf[0], sacc1, 0, 0, 0);
    sacc1 = __builtin_amdgcn_mfma_f32_16x16x32_bf16(kf3, qf[1], sacc1, 0, 0, 0);

    // ---- P = exp(S), pack to bf16 pairs
    unsigned u00 = cvtpk(__expf(sacc0[0]), __expf(sacc0[1]));  // mi=0 keys kq*4+{0,1}
    unsigned u01 = cvtpk(__expf(sacc0[2]), __expf(sacc0[3]));  // mi=0 keys kq*4+{2,3}
    unsigned u10 = cvtpk(__expf(sacc1[0]), __expf(sacc1[1]));  // mi=1
    unsigned u11 = cvtpk(__expf(sacc1[2]), __expf(sacc1[3]));  // mi=1

    // ---- l from the ROUNDED values (matches PV numerator rounding)
    l_acc += __uint_as_float(u00 << 16) + __uint_as_float(u00 & 0xffff0000u)
           + __uint_as_float(u01 << 16) + __uint_as_float(u01 & 0xffff0000u)
           + __uint_as_float(u10 << 16) + __uint_as_float(u10 & 0xffff0000u)
           + __uint_as_float(u11 << 16) + __uint_as_float(u11 & 0xffff0000u);

    // ---- intra-wave rearrange: shuffle BOTH halves, select by DEST's mi
    unsigned a0 = (unsigned)__shfl((int)u00, sb);
    unsigned b0 = (unsigned)__shfl((int)u10, sb);
    unsigned a1 = (unsigned)__shfl((int)u01, sb);
    unsigned b1 = (unsigned)__shfl((int)u11, sb);
    unsigned a2 = (unsigned)__shfl((int)u00, sb + 16);
    unsigned b2 = (unsigned)__shfl((int)u10, sb + 16);
    unsigned a3 = (unsigned)__shfl((int)u01, sb + 16);
    unsigned b3 = (unsigned)__shfl((int)u11, sb + 16);
    intx4 pw;
    pw.x = (int)(sel ? b0 : a0);
    pw.y = (int)(sel ? b1 : a1);
    pw.z = (int)(sel ? b2 : a2);
    pw.w = (int)(sel ? b3 : a3);
    union { intx4 i; short8 s; } pa;
    pa.i = pw;

    // ---- O += P.V (k = 32 keys, one mfma per d-block)
    oacc[0] = __builtin_amdgcn_mfma_f32_16x16x32_bf16(pa.s, vf0, oacc[0], 0, 0, 0);
    oacc[1] = __builtin_amdgcn_mfma_f32_16x16x32_bf16(pa.s, vf1, oacc[1], 0, 0, 0);
    oacc[2] = __builtin_amdgcn_mfma_f32_16x16x32_bf16(pa.s, vf2, oacc[2], 0, 0, 0);
    oacc[3] = __builtin_amdgcn_mfma_f32_16x16x32_bf16(pa.s, vf3, oacc[3], 0, 0, 0);
  }

  // ---- l: sum the 4 kq-copies; then fetch l[q=kq*4+r] from lane rr=q
  l_acc += __shfl_xor(l_acc, 16);
  l_acc += __shfl_xor(l_acc, 32);

  u16* aob = ao + ((size_t)(b * 256 + q0)) * 1024 + h * 64;
#pragma unroll
  for (int r = 0; r < 4; ++r) {
    float lv = __shfl(l_acc, kq * 4 + r);
    float inv = 1.0f / lv;
    int qrow_o = kq * 4 + r;
#pragma unroll
    for (int ni = 0; ni < 4; ++ni) {
      int d = ni * 16 + rr;
      aob[(size_t)qrow_o * 1024 + d] = f2bf(oacc[ni][r] * inv);
    }
  }
}

// ---- out-proj: out = ao @ w_out^T + b_out + queries (fp32), 64x128 tiles ----
__global__ __launch_bounds__(256, 2) void gemm_out(
    const u16* __restrict__ A, const u16* __restrict__ W,
    const float* __restrict__ bias, const float* __restrict__ resid,
    float* __restrict__ out) {
  __shared__ __attribute__((aligned(16))) u16 Alds[2 * 64 * 64];
  __shared__ __attribute__((aligned(16))) u16 Blds[2 * 128 * 64];
  const int mB = blockIdx.y * 64;
  const int nB = blockIdx.x * 128;
  const floatx4 zz = {0.f, 0.f, 0.f, 0.f};
  floatx4 acc[2][4] = {{zz, zz, zz, zz}, {zz, zz, zz, zz}};
  gemm_core<2, 4>(A + (size_t)mB * 1024, 1024, W + (size_t)nB * 1024, 1024, 1024,
                  Alds, Blds, acc);
  const int lane = threadIdx.x & 63, wave = threadIdx.x >> 6;
  const int rr = lane & 15, r4 = (lane >> 4) * 4;
  const int m0w = (wave & 1) * 32, n0w = (wave >> 1) * 64;
#pragma unroll
  for (int mi = 0; mi < 2; ++mi)
#pragma unroll
    for (int ni = 0; ni < 4; ++ni) {
      int n = nB + n0w + ni * 16 + rr;
      float bv = bias[n];
#pragma unroll
      for (int r = 0; r < 4; ++r) {
        int m = mB + m0w + mi * 16 + r4 + r;
        size_t idx = (size_t)m * 1024 + n;
        out[idx] = acc[mi][ni][r] + bv + resid[idx];
      }
    }
}

extern "C" void kernel_launch(void* const* d_in, const int* in_sizes, int n_in,
                              void* d_out, int out_size, void* d_ws, size_t ws_size,
                              hipStream_t stream) {
  const float* sources = (const float*)d_in[0];  // [8,2048,1024]
  const float* queries = (const float*)d_in[1];  // [8,256,1024]
  const float* w_in    = (const float*)d_in[2];  // [3072,1024]
  const float* b_in    = (const float*)d_in[3];  // [3072]
  const float* w_out   = (const float*)d_in[4];  // [1024,1024]
  const float* b_out   = (const float*)d_in[5];  // [1024]
  float* out = (float*)d_out;                    // [8,256,1024] fp32

  char* ws = (char*)d_ws;
  size_t off = 0;
  auto alloc = [&](size_t elems) -> u16* {
    u16* p = (u16*)(ws + off);
    off += elems * sizeof(u16);
    off = (off + 255) & ~(size_t)255;
    return p;
  };
  u16* s_bf  = alloc((size_t)16777216);  // sources bf16
  u16* qy_bf = alloc((size_t)2097152);   // queries bf16
  u16* wi_bf = alloc((size_t)3145728);   // w_in bf16
  u16* wo_bf = alloc((size_t)1048576);   // w_out bf16
  u16* qp    = alloc((size_t)2097152);   // projected q (pre-scaled 1/8)
  u16* kp    = alloc((size_t)16777216);  // projected k
  u16* vT    = alloc((size_t)16777216);  // projected v, [bh][d][n]
  u16* ao    = alloc((size_t)2097152);   // attention output

  // 1) casts
  f2bf_multi<<<dim3(22528), 256, 0, stream>>>(
      sources, s_bf, queries, qy_bf, w_in, wi_bf, w_out, wo_bf);

  // 2) projections (split: 512-block kv8 = 2 clean rounds, then small Q)
  gemm_proj_kv8<<<dim3(8, 64), 512, 0, stream>>>(s_bf, wi_bf, b_in, kp, vT);
  gemm_proj_q<<<dim3(8, 16), 256, 0, stream>>>(qy_bf, wi_bf, b_in, qp);

  // 3) fused attention v3-fixed (barrier-free, LDS-free, per-wave independent)
  attn_fused<<<dim3(512), 256, 0, stream>>>(qp, kp, vT, ao);

  // 4) out-proj + bias + residual
  gemm_out<<<dim3(8, 32), 256, 0, stream>>>(ao, wo_bf, b_out, queries, out);
}

// Round 10
// 273.784 us; speedup vs baseline: 1.2696x; 1.2696x over previous
//
#include <hip/hip_runtime.h>
#include <hip/hip_bf16.h>

// B=8, N=2048, Q=256, D=1024, H=16, HD=64 cross-attention.
// R16: attn_fused v4 = hybrid of the two VERIFIED halves:
//  - R11's coalesced LDS staging of K/V (R15's direct per-lane loads were
//    transaction-bound: 16 txn per wave-load, 121 us, MfmaUtil 5%),
//  - R15's in-register P path (shuffle rearrange verified: absmax 0.03125).
// Each wave owns 16 q end-to-end: S^T=mfma(K_lds,Q_reg) -> exp/cvt_pk ->
// 8-shfl rearrange -> PV from V_lds. P LDS buffer GONE, ONE barrier per
// 128-key tile (vs R11's two). 256 thr / 4 waves / 64q per block; 512 blocks;
// LDS 64 KB -> 2 blocks/CU. kv8 / proj_q / casts / out unchanged.

typedef unsigned short u16;
typedef __attribute__((ext_vector_type(8))) short short8;   // 8 bf16 = 4 VGPR
typedef __attribute__((ext_vector_type(4))) float floatx4;  // MFMA acc
typedef __attribute__((ext_vector_type(4))) int intx4;

static_assert(sizeof(short8) == 16, "short8 must be 16B");

__device__ __forceinline__ u16 f2bf(float f) {
  unsigned int x = __float_as_uint(f);
  x += 0x7fffu + ((x >> 16) & 1u);   // RNE
  return (u16)(x >> 16);
}

// pack 2 f32 -> 2 bf16 (RNE) in one instruction; elem0 = lo
__device__ __forceinline__ unsigned int cvtpk(float lo, float hi) {
  unsigned int r;
  asm("v_cvt_pk_bf16_f32 %0, %1, %2" : "=v"(r) : "v"(lo), "v"(hi));
  return r;
}

// async global->LDS, 16 B per lane; lds = wave-uniform base, lane i -> base+i*16
__device__ __forceinline__ void gload16(const u16* g, u16* lds) {
  __builtin_amdgcn_global_load_lds(
      (const __attribute__((address_space(1))) unsigned int*)g,
      (__attribute__((address_space(3))) unsigned int*)lds, 16, 0, 0);
}

template <int N> __device__ __forceinline__ void vmwait() {
  if constexpr (N == 0)      asm volatile("s_waitcnt vmcnt(0)" ::: "memory");
  else if constexpr (N == 4) asm volatile("s_waitcnt vmcnt(4)" ::: "memory");
  else if constexpr (N == 6) asm volatile("s_waitcnt vmcnt(6)" ::: "memory");
  else if constexpr (N == 8) asm volatile("s_waitcnt vmcnt(8)" ::: "memory");
  else static_assert(N == 0, "unsupported vmcnt immediate");
}

__device__ __forceinline__ void lgkm0() {
  asm volatile("s_waitcnt lgkmcnt(0)" ::: "memory");
}

__device__ __forceinline__ void sfence() { __builtin_amdgcn_sched_barrier(0); }

// ---------------- single fused fp32 -> bf16 cast over all 4 inputs ----------------
__global__ __launch_bounds__(256) void f2bf_multi(
    const float* __restrict__ s, u16* __restrict__ so,
    const float* __restrict__ q, u16* __restrict__ qo,
    const float* __restrict__ wi, u16* __restrict__ wio,
    const float* __restrict__ wo, u16* __restrict__ woo) {
  int i = blockIdx.x * 256 + threadIdx.x;
  const float* in; u16* out; int idx;
  if (i < 4194304)      { in = s;  out = so;  idx = i; }
  else if (i < 4718592) { in = q;  out = qo;  idx = i - 4194304; }
  else if (i < 5505024) { in = wi; out = wio; idx = i - 4718592; }
  else if (i < 5767168) { in = wo; out = woo; idx = i - 5505024; }
  else return;
  float4 v = reinterpret_cast<const float4*>(in)[idx];
  ushort4 o;
  o.x = f2bf(v.x); o.y = f2bf(v.y); o.z = f2bf(v.z); o.w = f2bf(v.w);
  reinterpret_cast<ushort4*>(out)[idx] = o;
}

// ---------------- 2-phase pipelined GEMM core: tile (MT*32)x(NT*32), BK=64 ----
template <int MT, int NT>
__device__ __forceinline__ void gemm_core(
    const u16* __restrict__ A, int lda,
    const u16* __restrict__ Bm, int ldb, int K,
    u16* __restrict__ Alds, u16* __restrict__ Blds,
    floatx4 (&acc)[MT][NT]) {
  const int t = threadIdx.x;
  const int wave = t >> 6, lane = t & 63;
  const int rr = lane & 15, kq = lane >> 4;
  constexpr int AI = MT, BI = NT;
  constexpr int AELEMS = MT * 32 * 64;
  constexpr int BELEMS = NT * 32 * 64;

  const u16* ag[AI]; u16* al[AI];
#pragma unroll
  for (int i = 0; i < AI; ++i) {
    int s = i * 256 + t;
    int row = s >> 3, c16 = s & 7;
    ag[i] = A + (size_t)row * lda + ((c16 ^ (row & 7)) * 8);
    al[i] = Alds + (size_t)(i * 256 + wave * 64) * 8;
  }
  const u16* bg[BI]; u16* blp[BI];
#pragma unroll
  for (int i = 0; i < BI; ++i) {
    int s = i * 256 + t;
    int row = s >> 3, c16 = s & 7;
    bg[i] = Bm + (size_t)row * ldb + ((c16 ^ (row & 7)) * 8);
    blp[i] = Blds + (size_t)(i * 256 + wave * 64) * 8;
  }

  const int m0w = (wave & 1) * (MT * 16);
  const int n0w = (wave >> 1) * (NT * 16);
  int aoff[MT][2], boff[NT][2];
#pragma unroll
  for (int mi = 0; mi < MT; ++mi) {
    int row = m0w + mi * 16 + rr;
#pragma unroll
    for (int kk = 0; kk < 2; ++kk)
      aoff[mi][kk] = row * 64 + (((kk * 4 + kq) ^ (row & 7)) * 8);
  }
#pragma unroll
  for (int ni = 0; ni < NT; ++ni) {
    int row = n0w + ni * 16 + rr;
#pragma unroll
    for (int kk = 0; kk < 2; ++kk)
      boff[ni][kk] = row * 64 + (((kk * 4 + kq) ^ (row & 7)) * 8);
  }

  auto compute = [&](int bs) {
    const u16* Ab = Alds + bs * AELEMS;
    const u16* Bb = Blds + bs * BELEMS;
#pragma unroll
    for (int kk = 0; kk < 2; ++kk) {
      short8 af[MT], bfr[NT];
#pragma unroll
      for (int mi = 0; mi < MT; ++mi)
        af[mi] = *reinterpret_cast<const short8*>(Ab + aoff[mi][kk]);
#pragma unroll
      for (int ni = 0; ni < NT; ++ni)
        bfr[ni] = *reinterpret_cast<const short8*>(Bb + boff[ni][kk]);
      __builtin_amdgcn_s_setprio(1);
#pragma unroll
      for (int mi = 0; mi < MT; ++mi)
#pragma unroll
        for (int ni = 0; ni < NT; ++ni)
          acc[mi][ni] = __builtin_amdgcn_mfma_f32_16x16x32_bf16(af[mi], bfr[ni], acc[mi][ni], 0, 0, 0);
      __builtin_amdgcn_s_setprio(0);
    }
  };

  const int nt = K >> 6;

#pragma unroll
  for (int i = 0; i < AI; ++i) gload16(ag[i], al[i]);
#pragma unroll
  for (int i = 0; i < BI; ++i) gload16(bg[i], blp[i]);

  int cur = 0;
#pragma unroll 1
  for (int tt = 0; tt < nt - 1; ++tt) {
    const int nxt = cur ^ 1;
    const int koff = (tt + 1) * 64;
#pragma unroll
    for (int i = 0; i < AI; ++i) gload16(ag[i] + koff, al[i] + nxt * AELEMS);
#pragma unroll
    for (int i = 0; i < BI; ++i) gload16(bg[i] + koff, blp[i] + nxt * BELEMS);
    sfence();
    vmwait<AI + BI>();
    __builtin_amdgcn_s_barrier();
    sfence();
    compute(cur);
    sfence();
    __builtin_amdgcn_s_barrier();
    cur = nxt;
  }
  sfence();
  vmwait<0>();
  __builtin_amdgcn_s_barrier();
  sfence();
  compute(cur);
}

// ================= 8-phase 256x256 K/V projection (R8/R11) =================
template <int LO>
__device__ __forceinline__ void read_a8(const u16* ab, int kcol0, int kcol1,
                                        short8 (&af)[8][2]) {
#pragma unroll
  for (int mi = 0; mi < 4; ++mi) {
    af[LO + mi][0] = *reinterpret_cast<const short8*>(ab + (LO + mi) * 1024 + kcol0);
    af[LO + mi][1] = *reinterpret_cast<const short8*>(ab + (LO + mi) * 1024 + kcol1);
  }
}

template <int LO>
__device__ __forceinline__ void read_b8(const u16* bb, int kcol0, int kcol1,
                                        short8 (&bf)[4][2]) {
#pragma unroll
  for (int ni = 0; ni < 2; ++ni) {
    bf[LO + ni][0] = *reinterpret_cast<const short8*>(bb + (LO + ni) * 1024 + kcol0);
    bf[LO + ni][1] = *reinterpret_cast<const short8*>(bb + (LO + ni) * 1024 + kcol1);
  }
}

template <int M0, int N0>
__device__ __forceinline__ void quad8(const short8 (&af)[8][2], const short8 (&bf)[4][2],
                                      floatx4 (&acc)[8][4]) {
  __builtin_amdgcn_s_setprio(1);
#pragma unroll
  for (int kk = 0; kk < 2; ++kk)
#pragma unroll
    for (int mi = 0; mi < 4; ++mi)
#pragma unroll
      for (int ni = 0; ni < 2; ++ni)
        acc[M0 + mi][N0 + ni] = __builtin_amdgcn_mfma_f32_16x16x32_bf16(
            af[M0 + mi][kk], bf[N0 + ni][kk], acc[M0 + mi][N0 + ni], 0, 0, 0);
  __builtin_amdgcn_s_setprio(0);
}

__global__ __launch_bounds__(512, 2) void gemm_proj_kv8(
    const u16* __restrict__ s_bf, const u16* __restrict__ wi_bf,
    const float* __restrict__ b_in,
    u16* __restrict__ kp, u16* __restrict__ vT) {
  __shared__ __attribute__((aligned(16))) u16 Alds[2 * 256 * 64];  // 64 KiB
  __shared__ __attribute__((aligned(16))) u16 Blds[2 * 256 * 64];  // 64 KiB

  int bid = blockIdx.y * 8 + blockIdx.x;
  int nb = (bid & 7) * 64 + (bid >> 3);
  const int by = nb >> 3, bx = nb & 7;
  const int mB = by * 256;
  const int nB = bx * 256;
  const u16* Ag = s_bf + (size_t)mB * 1024;
  const u16* Wg = wi_bf + (size_t)(1024 + nB) * 1024;
  const float* bias = b_in + 1024 + nB;

  const int t = threadIdx.x;
  const int w = t >> 6, lane = t & 63;
  const int rr = lane & 15, kq = lane >> 4;
  const int wr = w >> 2, wc = w & 3;

  const u16* ga[2][2]; const u16* gb[2][2];
#pragma unroll
  for (int h = 0; h < 2; ++h)
#pragma unroll
    for (int i = 0; i < 2; ++i) {
      int s = i * 512 + t;
      int row = h * 128 + (s >> 3), c16 = s & 7;
      ga[h][i] = Ag + (size_t)row * 1024 + ((c16 ^ (row & 7)) * 8);
      gb[h][i] = Wg + (size_t)row * 1024 + ((c16 ^ (row & 7)) * 8);
    }

#define STAGE_A8(j, h) { const int d_ = ((j) & 1) * 16384;                         \
    gload16(ga[h][0] + (size_t)(j) * 64, Alds + d_ + (h) * 8192 + w * 512);        \
    gload16(ga[h][1] + (size_t)(j) * 64, Alds + d_ + (h) * 8192 + 4096 + w * 512); }
#define STAGE_B8(j, h) { const int d_ = ((j) & 1) * 16384;                         \
    gload16(gb[h][0] + (size_t)(j) * 64, Blds + d_ + (h) * 8192 + w * 512);        \
    gload16(gb[h][1] + (size_t)(j) * 64, Blds + d_ + (h) * 8192 + 4096 + w * 512); }

  const int kcol0 = ((kq) ^ (rr & 7)) * 8;
  const int kcol1 = ((4 + kq) ^ (rr & 7)) * 8;
  const u16* abase = Alds + (wr * 128 + rr) * 64;
  const u16* bbase = Blds + (wc * 64 + rr) * 64;

  short8 af[8][2], bf[4][2];
  const floatx4 zz = {0.f, 0.f, 0.f, 0.f};
  floatx4 acc[8][4];
#pragma unroll
  for (int mi = 0; mi < 8; ++mi)
#pragma unroll
    for (int ni = 0; ni < 4; ++ni) acc[mi][ni] = zz;

  STAGE_A8(0, 0); STAGE_B8(0, 0); STAGE_A8(0, 1); STAGE_B8(0, 1);
  STAGE_A8(1, 0); STAGE_B8(1, 0);
  sfence();
  vmwait<4>();
  __builtin_amdgcn_s_barrier();
  sfence();

#pragma unroll 1
  for (int kt = 0; kt < 16; ++kt) {
    const int doff = (kt & 1) * 16384;
    const u16* ab = abase + doff;
    const u16* bb = bbase + doff;
    read_a8<0>(ab, kcol0, kcol1, af);
    read_b8<0>(bb, kcol0, kcol1, bf);
    if (kt + 1 < 16) STAGE_A8(kt + 1, 1);
    sfence();
    __builtin_amdgcn_s_barrier();
    lgkm0(); sfence();
    quad8<0, 0>(af, bf, acc);
    sfence();
    __builtin_amdgcn_s_barrier();
    sfence();
    read_a8<4>(ab, kcol0, kcol1, af);
    read_b8<2>(bb, kcol0, kcol1, bf);
    if (kt + 1 < 16) STAGE_B8(kt + 1, 1);
    sfence();
    __builtin_amdgcn_s_barrier();
    lgkm0(); sfence();
    quad8<0, 2>(af, bf, acc);
    sfence();
    __builtin_amdgcn_s_barrier();
    sfence();
    if (kt + 2 < 16) STAGE_A8(kt + 2, 0);
    sfence();
    __builtin_amdgcn_s_barrier();
    quad8<4, 0>(af, bf, acc);
    sfence();
    __builtin_amdgcn_s_barrier();
    sfence();
    if (kt + 2 < 16) { STAGE_B8(kt + 2, 0); sfence(); vmwait<4>(); }
    else             { sfence(); vmwait<0>(); }
    __builtin_amdgcn_s_barrier();
    quad8<4, 2>(af, bf, acc);
    sfence();
    __builtin_amdgcn_s_barrier();
    sfence();
  }
#undef STAGE_A8
#undef STAGE_B8

  const int r4 = kq * 4;
  const int m0w = wr * 128, n0w = wc * 64;
  if (nB < 1024) {
#pragma unroll
    for (int mi = 0; mi < 8; ++mi)
#pragma unroll
      for (int ni = 0; ni < 4; ++ni) {
        int nl = n0w + ni * 16 + rr;
        float bv = bias[nl];
#pragma unroll
        for (int r = 0; r < 4; ++r) {
          int m = mB + m0w + mi * 16 + r4 + r;
          kp[(size_t)m * 1024 + nB + nl] = f2bf(acc[mi][ni][r] + bv);
        }
      }
  } else {
#pragma unroll
    for (int mi = 0; mi < 8; ++mi)
#pragma unroll
      for (int ni = 0; ni < 4; ++ni) {
        int n2 = nB + n0w + ni * 16 + rr - 1024;
        int h = n2 >> 6, d = n2 & 63;
        float bv = bias[n0w + ni * 16 + rr];
        int m0 = mB + m0w + mi * 16 + r4;
        int b = m0 >> 11, j0 = m0 & 2047;
        ushort4 o;
        o.x = f2bf(acc[mi][ni][0] + bv);
        o.y = f2bf(acc[mi][ni][1] + bv);
        o.z = f2bf(acc[mi][ni][2] + bv);
        o.w = f2bf(acc[mi][ni][3] + bv);
        *reinterpret_cast<ushort4*>(
            vT + ((size_t)(b * 16 + h) * 64 + d) * 2048 + j0) = o;
      }
  }
}

// ---- Q projection: small (3% of proj FLOPs), 128^2 2-phase core ----
__global__ __launch_bounds__(256, 2) void gemm_proj_q(
    const u16* __restrict__ qy_bf, const u16* __restrict__ wi_bf,
    const float* __restrict__ b_in, u16* __restrict__ qp) {
  __shared__ __attribute__((aligned(16))) u16 Alds[2 * 128 * 64];
  __shared__ __attribute__((aligned(16))) u16 Blds[2 * 128 * 64];
  const int mB = blockIdx.y * 128;
  const int nB = blockIdx.x * 128;
  const u16* A = qy_bf + (size_t)mB * 1024;
  const u16* W = wi_bf + (size_t)nB * 1024;
  const float* bias = b_in + nB;

  const floatx4 zz = {0.f, 0.f, 0.f, 0.f};
  floatx4 acc[4][4] = {{zz, zz, zz, zz}, {zz, zz, zz, zz}, {zz, zz, zz, zz}, {zz, zz, zz, zz}};
  gemm_core<4, 4>(A, 1024, W, 1024, 1024, Alds, Blds, acc);

  const int lane = threadIdx.x & 63, wave = threadIdx.x >> 6;
  const int rr = lane & 15, r4 = (lane >> 4) * 4;
  const int m0w = (wave & 1) * 64, n0w = (wave >> 1) * 64;
#pragma unroll
  for (int mi = 0; mi < 4; ++mi)
#pragma unroll
    for (int ni = 0; ni < 4; ++ni) {
      int nl = n0w + ni * 16 + rr;
      float bv = bias[nl];
#pragma unroll
      for (int r = 0; r < 4; ++r) {
        int m = mB + m0w + mi * 16 + r4 + r;
        qp[(size_t)m * 1024 + nB + nl] = f2bf((acc[mi][ni][r] + bv) * 0.125f);
      }
    }
}

// ================= fused attention R16: LDS-staged K/V + in-register P =========
// 512 blocks = (b,h,qquad); 4 waves x 16q. Per 128-key tile: stage next K/V
// (coalesced gload16, 8/thread), each wave: 4x 32-key groups {4 ds_read kf,
// 4 S-MFMA, exp/cvtpk/shfl (R15-verified), 4 ds_read vf, 4 PV-MFMA, l adds}.
// ONE barrier per tile. No P buffer. LDS 64 KB -> 2 blocks/CU.
__global__ __launch_bounds__(256, 2) void attn_fused(
    const u16* __restrict__ qp, const u16* __restrict__ kp,
    const u16* __restrict__ vT, u16* __restrict__ ao) {
  __shared__ __attribute__((aligned(16))) u16 Klds[2][8192];  // [128key][64d]
  __shared__ __attribute__((aligned(16))) u16 Vlds[2][8192];  // [64d][128key]

  const int bid = blockIdx.x;
  const int nb = (bid & 7) * 64 + (bid >> 3);   // XCD-chunked
  const int bh = nb >> 2, qq = nb & 3;
  const int b = bh >> 4, h = bh & 15;

  const int t = threadIdx.x;
  const int w = t >> 6, lane = t & 63;
  const int rr = lane & 15, kq = lane >> 4;
  const int q0 = qq * 64 + w * 16;              // wave's q base in [0,256)
  const int swz = rr & 7;

  // Q fragment (B-operand), one-time per-lane load: q = q0+rr, d = kc*32+kq*8
  const u16* qrow = qp + ((size_t)(b * 256 + q0 + rr)) * 1024 + h * 64 + kq * 8;
  short8 qf0 = *reinterpret_cast<const short8*>(qrow);
  short8 qf1 = *reinterpret_cast<const short8*>(qrow + 32);

  // staging sources (inverse-swizzled global, linear LDS dest)
  const u16* kg[4]; const u16* vg[4];
  {
    const u16* kbase = kp + ((size_t)b * 2048) * 1024 + h * 64;
    const u16* vbase = vT + ((size_t)bh * 64) * 2048;
#pragma unroll
    for (int i = 0; i < 4; ++i) {
      int s = i * 256 + t;
      int r8 = s >> 3, c8 = s & 7;       // K: 128 rows x 8 slots
      int r16 = s >> 4, c16 = s & 15;    // V: 64 rows x 16 slots
      kg[i] = kbase + (size_t)r8 * 1024 + ((c8 ^ (r8 & 7)) * 8);
      vg[i] = vbase + (size_t)r16 * 2048 + ((c16 ^ (r16 & 7)) * 8);
    }
  }

#define STAGE(j) {                                                        \
    u16* kd = &Klds[(j) & 1][w * 512];                                    \
    u16* vd = &Vlds[(j) & 1][w * 512];                                    \
    _Pragma("unroll")                                                     \
    for (int i_ = 0; i_ < 4; ++i_) {                                      \
      gload16(kg[i_] + (size_t)(j) * 131072, kd + i_ * 2048);             \
      gload16(vg[i_] + (size_t)(j) * 128,    vd + i_ * 2048);             \
    } }

  const floatx4 zz = {0.f, 0.f, 0.f, 0.f};
  floatx4 oacc[4] = {zz, zz, zz, zz};
  float l_acc = 0.f;

  const int sel = kq >> 1;                  // DEST's mi half (R15-verified)
  const int sb = rr + ((kq & 1) << 5);      // src lane base

  // prologue: stage tile 0, wait, sync
  STAGE(0);
  sfence();
  vmwait<0>();
  __builtin_amdgcn_s_barrier();
  sfence();

#pragma unroll 1
  for (int kt = 0; kt < 16; ++kt) {
    const int buf = kt & 1;
    if (kt + 1 < 16) STAGE(kt + 1);
    sfence();
    const u16* Kb = &Klds[buf][0];
    const u16* Vb = &Vlds[buf][0];
#pragma unroll
    for (int g = 0; g < 4; ++g) {
      // ---- K frags from LDS: keys g*32 + mi*16 + rr, d = kc*32+kq*8
      const u16* krow0 = Kb + (g * 32 + rr) * 64;
      short8 kf00 = *reinterpret_cast<const short8*>(krow0 + ((kq ^ swz) * 8));
      short8 kf01 = *reinterpret_cast<const short8*>(krow0 + (((4 + kq) ^ swz) * 8));
      short8 kf10 = *reinterpret_cast<const short8*>(krow0 + 16 * 64 + ((kq ^ swz) * 8));
      short8 kf11 = *reinterpret_cast<const short8*>(krow0 + 16 * 64 + (((4 + kq) ^ swz) * 8));
      // ---- S^T = K.Q : sacc[mi][r] = S[key=g*32+mi*16+kq*4+r][q=rr]
      floatx4 sacc0 = zz, sacc1 = zz;
      sacc0 = __builtin_amdgcn_mfma_f32_16x16x32_bf16(kf00, qf0, sacc0, 0, 0, 0);
      sacc0 = __builtin_amdgcn_mfma_f32_16x16x32_bf16(kf01, qf1, sacc0, 0, 0, 0);
      sacc1 = __builtin_amdgcn_mfma_f32_16x16x32_bf16(kf10, qf0, sacc1, 0, 0, 0);
      sacc1 = __builtin_amdgcn_mfma_f32_16x16x32_bf16(kf11, qf1, sacc1, 0, 0, 0);

      // ---- P = exp(S), pack (R15-verified body)
      unsigned u00 = cvtpk(__expf(sacc0[0]), __expf(sacc0[1]));
      unsigned u01 = cvtpk(__expf(sacc0[2]), __expf(sacc0[3]));
      unsigned u10 = cvtpk(__expf(sacc1[0]), __expf(sacc1[1]));
      unsigned u11 = cvtpk(__expf(sacc1[2]), __expf(sacc1[3]));
      l_acc += __uint_as_float(u00 << 16) + __uint_as_float(u00 & 0xffff0000u)
             + __uint_as_float(u01 << 16) + __uint_as_float(u01 & 0xffff0000u)
             + __uint_as_float(u10 << 16) + __uint_as_float(u10 & 0xffff0000u)
             + __uint_as_float(u11 << 16) + __uint_as_float(u11 & 0xffff0000u);

      // ---- intra-wave rearrange: shuffle BOTH halves, select by DEST's mi
      unsigned a0 = (unsigned)__shfl((int)u00, sb);
      unsigned b0 = (unsigned)__shfl((int)u10, sb);
      unsigned a1 = (unsigned)__shfl((int)u01, sb);
      unsigned b1 = (unsigned)__shfl((int)u11, sb);
      unsigned a2 = (unsigned)__shfl((int)u00, sb + 16);
      unsigned b2 = (unsigned)__shfl((int)u10, sb + 16);
      unsigned a3 = (unsigned)__shfl((int)u01, sb + 16);
      unsigned b3 = (unsigned)__shfl((int)u11, sb + 16);
      intx4 pw;
      pw.x = (int)(sel ? b0 : a0);
      pw.y = (int)(sel ? b1 : a1);
      pw.z = (int)(sel ? b2 : a2);
      pw.w = (int)(sel ? b3 : a3);
      union { intx4 i; short8 s; } pa;
      pa.i = pw;

      // ---- V frags from LDS: d = ni*16+rr, key slot = g*4+kq
      const u16* vrow0 = Vb + rr * 128;
      short8 vf0 = *reinterpret_cast<const short8*>(vrow0 + (((g * 4 + kq) ^ swz) << 3));
      short8 vf1 = *reinterpret_cast<const short8*>(vrow0 + 16 * 128 + (((g * 4 + kq) ^ swz) << 3));
      short8 vf2 = *reinterpret_cast<const short8*>(vrow0 + 32 * 128 + (((g * 4 + kq) ^ swz) << 3));
      short8 vf3 = *reinterpret_cast<const short8*>(vrow0 + 48 * 128 + (((g * 4 + kq) ^ swz) << 3));

      // ---- O += P.V
      oacc[0] = __builtin_amdgcn_mfma_f32_16x16x32_bf16(pa.s, vf0, oacc[0], 0, 0, 0);
      oacc[1] = __builtin_amdgcn_mfma_f32_16x16x32_bf16(pa.s, vf1, oacc[1], 0, 0, 0);
      oacc[2] = __builtin_amdgcn_mfma_f32_16x16x32_bf16(pa.s, vf2, oacc[2], 0, 0, 0);
      oacc[3] = __builtin_amdgcn_mfma_f32_16x16x32_bf16(pa.s, vf3, oacc[3], 0, 0, 0);
    }
    // one barrier per tile: staged loads landed (per-wave) + all reads done
    sfence();
    vmwait<0>();
    __builtin_amdgcn_s_barrier();
    sfence();
  }
#undef STAGE

  // ---- l: sum the 4 kq-copies; then fetch l[q=kq*4+r] from lane rr=q
  l_acc += __shfl_xor(l_acc, 16);
  l_acc += __shfl_xor(l_acc, 32);

  u16* aob = ao + ((size_t)(b * 256 + q0)) * 1024 + h * 64;
#pragma unroll
  for (int r = 0; r < 4; ++r) {
    float lv = __shfl(l_acc, kq * 4 + r);
    float inv = 1.0f / lv;
    int qrow_o = kq * 4 + r;
#pragma unroll
    for (int ni = 0; ni < 4; ++ni) {
      int d = ni * 16 + rr;
      aob[(size_t)qrow_o * 1024 + d] = f2bf(oacc[ni][r] * inv);
    }
  }
}

// ---- out-proj: out = ao @ w_out^T + b_out + queries (fp32), 64x128 tiles ----
__global__ __launch_bounds__(256, 2) void gemm_out(
    const u16* __restrict__ A, const u16* __restrict__ W,
    const float* __restrict__ bias, const float* __restrict__ resid,
    float* __restrict__ out) {
  __shared__ __attribute__((aligned(16))) u16 Alds[2 * 64 * 64];
  __shared__ __attribute__((aligned(16))) u16 Blds[2 * 128 * 64];
  const int mB = blockIdx.y * 64;
  const int nB = blockIdx.x * 128;
  const floatx4 zz = {0.f, 0.f, 0.f, 0.f};
  floatx4 acc[2][4] = {{zz, zz, zz, zz}, {zz, zz, zz, zz}};
  gemm_core<2, 4>(A + (size_t)mB * 1024, 1024, W + (size_t)nB * 1024, 1024, 1024,
                  Alds, Blds, acc);
  const int lane = threadIdx.x & 63, wave = threadIdx.x >> 6;
  const int rr = lane & 15, r4 = (lane >> 4) * 4;
  const int m0w = (wave & 1) * 32, n0w = (wave >> 1) * 64;
#pragma unroll
  for (int mi = 0; mi < 2; ++mi)
#pragma unroll
    for (int ni = 0; ni < 4; ++ni) {
      int n = nB + n0w + ni * 16 + rr;
      float bv = bias[n];
#pragma unroll
      for (int r = 0; r < 4; ++r) {
        int m = mB + m0w + mi * 16 + r4 + r;
        size_t idx = (size_t)m * 1024 + n;
        out[idx] = acc[mi][ni][r] + bv + resid[idx];
      }
    }
}

extern "C" void kernel_launch(void* const* d_in, const int* in_sizes, int n_in,
                              void* d_out, int out_size, void* d_ws, size_t ws_size,
                              hipStream_t stream) {
  const float* sources = (const float*)d_in[0];  // [8,2048,1024]
  const float* queries = (const float*)d_in[1];  // [8,256,1024]
  const float* w_in    = (const float*)d_in[2];  // [3072,1024]
  const float* b_in    = (const float*)d_in[3];  // [3072]
  const float* w_out   = (const float*)d_in[4];  // [1024,1024]
  const float* b_out   = (const float*)d_in[5];  // [1024]
  float* out = (float*)d_out;                    // [8,256,1024] fp32

  char* ws = (char*)d_ws;
  size_t off = 0;
  auto alloc = [&](size_t elems) -> u16* {
    u16* p = (u16*)(ws + off);
    off += elems * sizeof(u16);
    off = (off + 255) & ~(size_t)255;
    return p;
  };
  u16* s_bf  = alloc((size_t)16777216);  // sources bf16
  u16* qy_bf = alloc((size_t)2097152);   // queries bf16
  u16* wi_bf = alloc((size_t)3145728);   // w_in bf16
  u16* wo_bf = alloc((size_t)1048576);   // w_out bf16
  u16* qp    = alloc((size_t)2097152);   // projected q (pre-scaled 1/8)
  u16* kp    = alloc((size_t)16777216);  // projected k
  u16* vT    = alloc((size_t)16777216);  // projected v, [bh][d][n]
  u16* ao    = alloc((size_t)2097152);   // attention output

  // 1) casts
  f2bf_multi<<<dim3(22528), 256, 0, stream>>>(
      sources, s_bf, queries, qy_bf, w_in, wi_bf, w_out, wo_bf);

  // 2) projections (split: 512-block kv8 = 2 clean rounds, then small Q)
  gemm_proj_kv8<<<dim3(8, 64), 512, 0, stream>>>(s_bf, wi_bf, b_in, kp, vT);
  gemm_proj_q<<<dim3(8, 16), 256, 0, stream>>>(qy_bf, wi_bf, b_in, qp);

  // 3) fused attention v4 (LDS-staged K/V + in-register P, 1 barrier/tile)
  attn_fused<<<dim3(512), 256, 0, stream>>>(qp, kp, vT, ao);

  // 4) out-proj + bias + residual
  gemm_out<<<dim3(8, 32), 256, 0, stream>>>(ao, wo_bf, b_out, queries, out);
}

// Round 11
// 263.603 us; speedup vs baseline: 1.3186x; 1.0386x over previous
//
#include <hip/hip_runtime.h>
#include <hip/hip_bf16.h>

// B=8, N=2048, Q=256, D=1024, H=16, HD=64 cross-attention.
// R17: proj_q and gemm_out rebuilt as 64x64-tile / 4-blocks-per-CU versions
// (gemm_core<2,2>, 512 blocks each). Diagnosis: at 128-256 blocks these
// kernels ran 1 wave/SIMD -- the 2-phase K-loop's vmwait+barrier critical
// path had zero TLP to hide it (~20 us each vs 1.7 us MFMA floor). Same
// proven core, same per-element K accumulation chain (bit-identical output).
// casts / kv8 / attn_fused byte-identical to R16 for isolation.

typedef unsigned short u16;
typedef __attribute__((ext_vector_type(8))) short short8;   // 8 bf16 = 4 VGPR
typedef __attribute__((ext_vector_type(4))) float floatx4;  // MFMA acc
typedef __attribute__((ext_vector_type(4))) int intx4;

static_assert(sizeof(short8) == 16, "short8 must be 16B");

__device__ __forceinline__ u16 f2bf(float f) {
  unsigned int x = __float_as_uint(f);
  x += 0x7fffu + ((x >> 16) & 1u);   // RNE
  return (u16)(x >> 16);
}

// pack 2 f32 -> 2 bf16 (RNE) in one instruction; elem0 = lo
__device__ __forceinline__ unsigned int cvtpk(float lo, float hi) {
  unsigned int r;
  asm("v_cvt_pk_bf16_f32 %0, %1, %2" : "=v"(r) : "v"(lo), "v"(hi));
  return r;
}

// async global->LDS, 16 B per lane; lds = wave-uniform base, lane i -> base+i*16
__device__ __forceinline__ void gload16(const u16* g, u16* lds) {
  __builtin_amdgcn_global_load_lds(
      (const __attribute__((address_space(1))) unsigned int*)g,
      (__attribute__((address_space(3))) unsigned int*)lds, 16, 0, 0);
}

template <int N> __device__ __forceinline__ void vmwait() {
  if constexpr (N == 0)      asm volatile("s_waitcnt vmcnt(0)" ::: "memory");
  else if constexpr (N == 4) asm volatile("s_waitcnt vmcnt(4)" ::: "memory");
  else if constexpr (N == 6) asm volatile("s_waitcnt vmcnt(6)" ::: "memory");
  else if constexpr (N == 8) asm volatile("s_waitcnt vmcnt(8)" ::: "memory");
  else static_assert(N == 0, "unsupported vmcnt immediate");
}

__device__ __forceinline__ void lgkm0() {
  asm volatile("s_waitcnt lgkmcnt(0)" ::: "memory");
}

__device__ __forceinline__ void sfence() { __builtin_amdgcn_sched_barrier(0); }

// ---------------- single fused fp32 -> bf16 cast over all 4 inputs ----------------
__global__ __launch_bounds__(256) void f2bf_multi(
    const float* __restrict__ s, u16* __restrict__ so,
    const float* __restrict__ q, u16* __restrict__ qo,
    const float* __restrict__ wi, u16* __restrict__ wio,
    const float* __restrict__ wo, u16* __restrict__ woo) {
  int i = blockIdx.x * 256 + threadIdx.x;
  const float* in; u16* out; int idx;
  if (i < 4194304)      { in = s;  out = so;  idx = i; }
  else if (i < 4718592) { in = q;  out = qo;  idx = i - 4194304; }
  else if (i < 5505024) { in = wi; out = wio; idx = i - 4718592; }
  else if (i < 5767168) { in = wo; out = woo; idx = i - 5505024; }
  else return;
  float4 v = reinterpret_cast<const float4*>(in)[idx];
  ushort4 o;
  o.x = f2bf(v.x); o.y = f2bf(v.y); o.z = f2bf(v.z); o.w = f2bf(v.w);
  reinterpret_cast<ushort4*>(out)[idx] = o;
}

// ---------------- 2-phase pipelined GEMM core: tile (MT*32)x(NT*32), BK=64 ----
template <int MT, int NT>
__device__ __forceinline__ void gemm_core(
    const u16* __restrict__ A, int lda,
    const u16* __restrict__ Bm, int ldb, int K,
    u16* __restrict__ Alds, u16* __restrict__ Blds,
    floatx4 (&acc)[MT][NT]) {
  const int t = threadIdx.x;
  const int wave = t >> 6, lane = t & 63;
  const int rr = lane & 15, kq = lane >> 4;
  constexpr int AI = MT, BI = NT;
  constexpr int AELEMS = MT * 32 * 64;
  constexpr int BELEMS = NT * 32 * 64;

  const u16* ag[AI]; u16* al[AI];
#pragma unroll
  for (int i = 0; i < AI; ++i) {
    int s = i * 256 + t;
    int row = s >> 3, c16 = s & 7;
    ag[i] = A + (size_t)row * lda + ((c16 ^ (row & 7)) * 8);
    al[i] = Alds + (size_t)(i * 256 + wave * 64) * 8;
  }
  const u16* bg[BI]; u16* blp[BI];
#pragma unroll
  for (int i = 0; i < BI; ++i) {
    int s = i * 256 + t;
    int row = s >> 3, c16 = s & 7;
    bg[i] = Bm + (size_t)row * ldb + ((c16 ^ (row & 7)) * 8);
    blp[i] = Blds + (size_t)(i * 256 + wave * 64) * 8;
  }

  const int m0w = (wave & 1) * (MT * 16);
  const int n0w = (wave >> 1) * (NT * 16);
  int aoff[MT][2], boff[NT][2];
#pragma unroll
  for (int mi = 0; mi < MT; ++mi) {
    int row = m0w + mi * 16 + rr;
#pragma unroll
    for (int kk = 0; kk < 2; ++kk)
      aoff[mi][kk] = row * 64 + (((kk * 4 + kq) ^ (row & 7)) * 8);
  }
#pragma unroll
  for (int ni = 0; ni < NT; ++ni) {
    int row = n0w + ni * 16 + rr;
#pragma unroll
    for (int kk = 0; kk < 2; ++kk)
      boff[ni][kk] = row * 64 + (((kk * 4 + kq) ^ (row & 7)) * 8);
  }

  auto compute = [&](int bs) {
    const u16* Ab = Alds + bs * AELEMS;
    const u16* Bb = Blds + bs * BELEMS;
#pragma unroll
    for (int kk = 0; kk < 2; ++kk) {
      short8 af[MT], bfr[NT];
#pragma unroll
      for (int mi = 0; mi < MT; ++mi)
        af[mi] = *reinterpret_cast<const short8*>(Ab + aoff[mi][kk]);
#pragma unroll
      for (int ni = 0; ni < NT; ++ni)
        bfr[ni] = *reinterpret_cast<const short8*>(Bb + boff[ni][kk]);
      __builtin_amdgcn_s_setprio(1);
#pragma unroll
      for (int mi = 0; mi < MT; ++mi)
#pragma unroll
        for (int ni = 0; ni < NT; ++ni)
          acc[mi][ni] = __builtin_amdgcn_mfma_f32_16x16x32_bf16(af[mi], bfr[ni], acc[mi][ni], 0, 0, 0);
      __builtin_amdgcn_s_setprio(0);
    }
  };

  const int nt = K >> 6;

#pragma unroll
  for (int i = 0; i < AI; ++i) gload16(ag[i], al[i]);
#pragma unroll
  for (int i = 0; i < BI; ++i) gload16(bg[i], blp[i]);

  int cur = 0;
#pragma unroll 1
  for (int tt = 0; tt < nt - 1; ++tt) {
    const int nxt = cur ^ 1;
    const int koff = (tt + 1) * 64;
#pragma unroll
    for (int i = 0; i < AI; ++i) gload16(ag[i] + koff, al[i] + nxt * AELEMS);
#pragma unroll
    for (int i = 0; i < BI; ++i) gload16(bg[i] + koff, blp[i] + nxt * BELEMS);
    sfence();
    vmwait<AI + BI>();
    __builtin_amdgcn_s_barrier();
    sfence();
    compute(cur);
    sfence();
    __builtin_amdgcn_s_barrier();
    cur = nxt;
  }
  sfence();
  vmwait<0>();
  __builtin_amdgcn_s_barrier();
  sfence();
  compute(cur);
}

// ================= 8-phase 256x256 K/V projection (R8/R11) =================
template <int LO>
__device__ __forceinline__ void read_a8(const u16* ab, int kcol0, int kcol1,
                                        short8 (&af)[8][2]) {
#pragma unroll
  for (int mi = 0; mi < 4; ++mi) {
    af[LO + mi][0] = *reinterpret_cast<const short8*>(ab + (LO + mi) * 1024 + kcol0);
    af[LO + mi][1] = *reinterpret_cast<const short8*>(ab + (LO + mi) * 1024 + kcol1);
  }
}

template <int LO>
__device__ __forceinline__ void read_b8(const u16* bb, int kcol0, int kcol1,
                                        short8 (&bf)[4][2]) {
#pragma unroll
  for (int ni = 0; ni < 2; ++ni) {
    bf[LO + ni][0] = *reinterpret_cast<const short8*>(bb + (LO + ni) * 1024 + kcol0);
    bf[LO + ni][1] = *reinterpret_cast<const short8*>(bb + (LO + ni) * 1024 + kcol1);
  }
}

template <int M0, int N0>
__device__ __forceinline__ void quad8(const short8 (&af)[8][2], const short8 (&bf)[4][2],
                                      floatx4 (&acc)[8][4]) {
  __builtin_amdgcn_s_setprio(1);
#pragma unroll
  for (int kk = 0; kk < 2; ++kk)
#pragma unroll
    for (int mi = 0; mi < 4; ++mi)
#pragma unroll
      for (int ni = 0; ni < 2; ++ni)
        acc[M0 + mi][N0 + ni] = __builtin_amdgcn_mfma_f32_16x16x32_bf16(
            af[M0 + mi][kk], bf[N0 + ni][kk], acc[M0 + mi][N0 + ni], 0, 0, 0);
  __builtin_amdgcn_s_setprio(0);
}

__global__ __launch_bounds__(512, 2) void gemm_proj_kv8(
    const u16* __restrict__ s_bf, const u16* __restrict__ wi_bf,
    const float* __restrict__ b_in,
    u16* __restrict__ kp, u16* __restrict__ vT) {
  __shared__ __attribute__((aligned(16))) u16 Alds[2 * 256 * 64];  // 64 KiB
  __shared__ __attribute__((aligned(16))) u16 Blds[2 * 256 * 64];  // 64 KiB

  int bid = blockIdx.y * 8 + blockIdx.x;
  int nb = (bid & 7) * 64 + (bid >> 3);
  const int by = nb >> 3, bx = nb & 7;
  const int mB = by * 256;
  const int nB = bx * 256;
  const u16* Ag = s_bf + (size_t)mB * 1024;
  const u16* Wg = wi_bf + (size_t)(1024 + nB) * 1024;
  const float* bias = b_in + 1024 + nB;

  const int t = threadIdx.x;
  const int w = t >> 6, lane = t & 63;
  const int rr = lane & 15, kq = lane >> 4;
  const int wr = w >> 2, wc = w & 3;

  const u16* ga[2][2]; const u16* gb[2][2];
#pragma unroll
  for (int h = 0; h < 2; ++h)
#pragma unroll
    for (int i = 0; i < 2; ++i) {
      int s = i * 512 + t;
      int row = h * 128 + (s >> 3), c16 = s & 7;
      ga[h][i] = Ag + (size_t)row * 1024 + ((c16 ^ (row & 7)) * 8);
      gb[h][i] = Wg + (size_t)row * 1024 + ((c16 ^ (row & 7)) * 8);
    }

#define STAGE_A8(j, h) { const int d_ = ((j) & 1) * 16384;                         \
    gload16(ga[h][0] + (size_t)(j) * 64, Alds + d_ + (h) * 8192 + w * 512);        \
    gload16(ga[h][1] + (size_t)(j) * 64, Alds + d_ + (h) * 8192 + 4096 + w * 512); }
#define STAGE_B8(j, h) { const int d_ = ((j) & 1) * 16384;                         \
    gload16(gb[h][0] + (size_t)(j) * 64, Blds + d_ + (h) * 8192 + w * 512);        \
    gload16(gb[h][1] + (size_t)(j) * 64, Blds + d_ + (h) * 8192 + 4096 + w * 512); }

  const int kcol0 = ((kq) ^ (rr & 7)) * 8;
  const int kcol1 = ((4 + kq) ^ (rr & 7)) * 8;
  const u16* abase = Alds + (wr * 128 + rr) * 64;
  const u16* bbase = Blds + (wc * 64 + rr) * 64;

  short8 af[8][2], bf[4][2];
  const floatx4 zz = {0.f, 0.f, 0.f, 0.f};
  floatx4 acc[8][4];
#pragma unroll
  for (int mi = 0; mi < 8; ++mi)
#pragma unroll
    for (int ni = 0; ni < 4; ++ni) acc[mi][ni] = zz;

  STAGE_A8(0, 0); STAGE_B8(0, 0); STAGE_A8(0, 1); STAGE_B8(0, 1);
  STAGE_A8(1, 0); STAGE_B8(1, 0);
  sfence();
  vmwait<4>();
  __builtin_amdgcn_s_barrier();
  sfence();

#pragma unroll 1
  for (int kt = 0; kt < 16; ++kt) {
    const int doff = (kt & 1) * 16384;
    const u16* ab = abase + doff;
    const u16* bb = bbase + doff;
    read_a8<0>(ab, kcol0, kcol1, af);
    read_b8<0>(bb, kcol0, kcol1, bf);
    if (kt + 1 < 16) STAGE_A8(kt + 1, 1);
    sfence();
    __builtin_amdgcn_s_barrier();
    lgkm0(); sfence();
    quad8<0, 0>(af, bf, acc);
    sfence();
    __builtin_amdgcn_s_barrier();
    sfence();
    read_a8<4>(ab, kcol0, kcol1, af);
    read_b8<2>(bb, kcol0, kcol1, bf);
    if (kt + 1 < 16) STAGE_B8(kt + 1, 1);
    sfence();
    __builtin_amdgcn_s_barrier();
    lgkm0(); sfence();
    quad8<0, 2>(af, bf, acc);
    sfence();
    __builtin_amdgcn_s_barrier();
    sfence();
    if (kt + 2 < 16) STAGE_A8(kt + 2, 0);
    sfence();
    __builtin_amdgcn_s_barrier();
    quad8<4, 0>(af, bf, acc);
    sfence();
    __builtin_amdgcn_s_barrier();
    sfence();
    if (kt + 2 < 16) { STAGE_B8(kt + 2, 0); sfence(); vmwait<4>(); }
    else             { sfence(); vmwait<0>(); }
    __builtin_amdgcn_s_barrier();
    quad8<4, 2>(af, bf, acc);
    sfence();
    __builtin_amdgcn_s_barrier();
    sfence();
  }
#undef STAGE_A8
#undef STAGE_B8

  const int r4 = kq * 4;
  const int m0w = wr * 128, n0w = wc * 64;
  if (nB < 1024) {
#pragma unroll
    for (int mi = 0; mi < 8; ++mi)
#pragma unroll
      for (int ni = 0; ni < 4; ++ni) {
        int nl = n0w + ni * 16 + rr;
        float bv = bias[nl];
#pragma unroll
        for (int r = 0; r < 4; ++r) {
          int m = mB + m0w + mi * 16 + r4 + r;
          kp[(size_t)m * 1024 + nB + nl] = f2bf(acc[mi][ni][r] + bv);
        }
      }
  } else {
#pragma unroll
    for (int mi = 0; mi < 8; ++mi)
#pragma unroll
      for (int ni = 0; ni < 4; ++ni) {
        int n2 = nB + n0w + ni * 16 + rr - 1024;
        int h = n2 >> 6, d = n2 & 63;
        float bv = bias[n0w + ni * 16 + rr];
        int m0 = mB + m0w + mi * 16 + r4;
        int b = m0 >> 11, j0 = m0 & 2047;
        ushort4 o;
        o.x = f2bf(acc[mi][ni][0] + bv);
        o.y = f2bf(acc[mi][ni][1] + bv);
        o.z = f2bf(acc[mi][ni][2] + bv);
        o.w = f2bf(acc[mi][ni][3] + bv);
        *reinterpret_cast<ushort4*>(
            vT + ((size_t)(b * 16 + h) * 64 + d) * 2048 + j0) = o;
      }
  }
}

// ---- Q projection: 64x64 tiles, 512 blocks, 4 blocks/CU (TLP hides K-loop) ----
__global__ __launch_bounds__(256, 4) void gemm_proj_q(
    const u16* __restrict__ qy_bf, const u16* __restrict__ wi_bf,
    const float* __restrict__ b_in, u16* __restrict__ qp) {
  __shared__ __attribute__((aligned(16))) u16 Alds[2 * 64 * 64];
  __shared__ __attribute__((aligned(16))) u16 Blds[2 * 64 * 64];
  const int mB = blockIdx.y * 64;
  const int nB = blockIdx.x * 64;
  const u16* A = qy_bf + (size_t)mB * 1024;
  const u16* W = wi_bf + (size_t)nB * 1024;
  const float* bias = b_in + nB;

  const floatx4 zz = {0.f, 0.f, 0.f, 0.f};
  floatx4 acc[2][2] = {{zz, zz}, {zz, zz}};
  gemm_core<2, 2>(A, 1024, W, 1024, 1024, Alds, Blds, acc);

  const int lane = threadIdx.x & 63, wave = threadIdx.x >> 6;
  const int rr = lane & 15, r4 = (lane >> 4) * 4;
  const int m0w = (wave & 1) * 32, n0w = (wave >> 1) * 32;
#pragma unroll
  for (int mi = 0; mi < 2; ++mi)
#pragma unroll
    for (int ni = 0; ni < 2; ++ni) {
      int nl = n0w + ni * 16 + rr;
      float bv = bias[nl];
#pragma unroll
      for (int r = 0; r < 4; ++r) {
        int m = mB + m0w + mi * 16 + r4 + r;
        qp[(size_t)m * 1024 + nB + nl] = f2bf((acc[mi][ni][r] + bv) * 0.125f);
      }
    }
}

// ================= fused attention R16: LDS-staged K/V + in-register P =========
// 512 blocks = (b,h,qquad); 4 waves x 16q. Per 128-key tile: stage next K/V
// (coalesced gload16, 8/thread), each wave: 4x 32-key groups {4 ds_read kf,
// 4 S-MFMA, exp/cvtpk/shfl (R15-verified), 4 ds_read vf, 4 PV-MFMA, l adds}.
// ONE barrier per tile. No P buffer. LDS 64 KB -> 2 blocks/CU.
__global__ __launch_bounds__(256, 2) void attn_fused(
    const u16* __restrict__ qp, const u16* __restrict__ kp,
    const u16* __restrict__ vT, u16* __restrict__ ao) {
  __shared__ __attribute__((aligned(16))) u16 Klds[2][8192];  // [128key][64d]
  __shared__ __attribute__((aligned(16))) u16 Vlds[2][8192];  // [64d][128key]

  const int bid = blockIdx.x;
  const int nb = (bid & 7) * 64 + (bid >> 3);   // XCD-chunked
  const int bh = nb >> 2, qq = nb & 3;
  const int b = bh >> 4, h = bh & 15;

  const int t = threadIdx.x;
  const int w = t >> 6, lane = t & 63;
  const int rr = lane & 15, kq = lane >> 4;
  const int q0 = qq * 64 + w * 16;              // wave's q base in [0,256)
  const int swz = rr & 7;

  // Q fragment (B-operand), one-time per-lane load: q = q0+rr, d = kc*32+kq*8
  const u16* qrow = qp + ((size_t)(b * 256 + q0 + rr)) * 1024 + h * 64 + kq * 8;
  short8 qf0 = *reinterpret_cast<const short8*>(qrow);
  short8 qf1 = *reinterpret_cast<const short8*>(qrow + 32);

  // staging sources (inverse-swizzled global, linear LDS dest)
  const u16* kg[4]; const u16* vg[4];
  {
    const u16* kbase = kp + ((size_t)b * 2048) * 1024 + h * 64;
    const u16* vbase = vT + ((size_t)bh * 64) * 2048;
#pragma unroll
    for (int i = 0; i < 4; ++i) {
      int s = i * 256 + t;
      int r8 = s >> 3, c8 = s & 7;       // K: 128 rows x 8 slots
      int r16 = s >> 4, c16 = s & 15;    // V: 64 rows x 16 slots
      kg[i] = kbase + (size_t)r8 * 1024 + ((c8 ^ (r8 & 7)) * 8);
      vg[i] = vbase + (size_t)r16 * 2048 + ((c16 ^ (r16 & 7)) * 8);
    }
  }

#define STAGE(j) {                                                        \
    u16* kd = &Klds[(j) & 1][w * 512];                                    \
    u16* vd = &Vlds[(j) & 1][w * 512];                                    \
    _Pragma("unroll")                                                     \
    for (int i_ = 0; i_ < 4; ++i_) {                                      \
      gload16(kg[i_] + (size_t)(j) * 131072, kd + i_ * 2048);             \
      gload16(vg[i_] + (size_t)(j) * 128,    vd + i_ * 2048);             \
    } }

  const floatx4 zz = {0.f, 0.f, 0.f, 0.f};
  floatx4 oacc[4] = {zz, zz, zz, zz};
  float l_acc = 0.f;

  const int sel = kq >> 1;                  // DEST's mi half (R15-verified)
  const int sb = rr + ((kq & 1) << 5);      // src lane base

  // prologue: stage tile 0, wait, sync
  STAGE(0);
  sfence();
  vmwait<0>();
  __builtin_amdgcn_s_barrier();
  sfence();

#pragma unroll 1
  for (int kt = 0; kt < 16; ++kt) {
    const int buf = kt & 1;
    if (kt + 1 < 16) STAGE(kt + 1);
    sfence();
    const u16* Kb = &Klds[buf][0];
    const u16* Vb = &Vlds[buf][0];
#pragma unroll
    for (int g = 0; g < 4; ++g) {
      // ---- K frags from LDS: keys g*32 + mi*16 + rr, d = kc*32+kq*8
      const u16* krow0 = Kb + (g * 32 + rr) * 64;
      short8 kf00 = *reinterpret_cast<const short8*>(krow0 + ((kq ^ swz) * 8));
      short8 kf01 = *reinterpret_cast<const short8*>(krow0 + (((4 + kq) ^ swz) * 8));
      short8 kf10 = *reinterpret_cast<const short8*>(krow0 + 16 * 64 + ((kq ^ swz) * 8));
      short8 kf11 = *reinterpret_cast<const short8*>(krow0 + 16 * 64 + (((4 + kq) ^ swz) * 8));
      // ---- S^T = K.Q : sacc[mi][r] = S[key=g*32+mi*16+kq*4+r][q=rr]
      floatx4 sacc0 = zz, sacc1 = zz;
      sacc0 = __builtin_amdgcn_mfma_f32_16x16x32_bf16(kf00, qf0, sacc0, 0, 0, 0);
      sacc0 = __builtin_amdgcn_mfma_f32_16x16x32_bf16(kf01, qf1, sacc0, 0, 0, 0);
      sacc1 = __builtin_amdgcn_mfma_f32_16x16x32_bf16(kf10, qf0, sacc1, 0, 0, 0);
      sacc1 = __builtin_amdgcn_mfma_f32_16x16x32_bf16(kf11, qf1, sacc1, 0, 0, 0);

      // ---- P = exp(S), pack (R15-verified body)
      unsigned u00 = cvtpk(__expf(sacc0[0]), __expf(sacc0[1]));
      unsigned u01 = cvtpk(__expf(sacc0[2]), __expf(sacc0[3]));
      unsigned u10 = cvtpk(__expf(sacc1[0]), __expf(sacc1[1]));
      unsigned u11 = cvtpk(__expf(sacc1[2]), __expf(sacc1[3]));
      l_acc += __uint_as_float(u00 << 16) + __uint_as_float(u00 & 0xffff0000u)
             + __uint_as_float(u01 << 16) + __uint_as_float(u01 & 0xffff0000u)
             + __uint_as_float(u10 << 16) + __uint_as_float(u10 & 0xffff0000u)
             + __uint_as_float(u11 << 16) + __uint_as_float(u11 & 0xffff0000u);

      // ---- intra-wave rearrange: shuffle BOTH halves, select by DEST's mi
      unsigned a0 = (unsigned)__shfl((int)u00, sb);
      unsigned b0 = (unsigned)__shfl((int)u10, sb);
      unsigned a1 = (unsigned)__shfl((int)u01, sb);
      unsigned b1 = (unsigned)__shfl((int)u11, sb);
      unsigned a2 = (unsigned)__shfl((int)u00, sb + 16);
      unsigned b2 = (unsigned)__shfl((int)u10, sb + 16);
      unsigned a3 = (unsigned)__shfl((int)u01, sb + 16);
      unsigned b3 = (unsigned)__shfl((int)u11, sb + 16);
      intx4 pw;
      pw.x = (int)(sel ? b0 : a0);
      pw.y = (int)(sel ? b1 : a1);
      pw.z = (int)(sel ? b2 : a2);
      pw.w = (int)(sel ? b3 : a3);
      union { intx4 i; short8 s; } pa;
      pa.i = pw;

      // ---- V frags from LDS: d = ni*16+rr, key slot = g*4+kq
      const u16* vrow0 = Vb + rr * 128;
      short8 vf0 = *reinterpret_cast<const short8*>(vrow0 + (((g * 4 + kq) ^ swz) << 3));
      short8 vf1 = *reinterpret_cast<const short8*>(vrow0 + 16 * 128 + (((g * 4 + kq) ^ swz) << 3));
      short8 vf2 = *reinterpret_cast<const short8*>(vrow0 + 32 * 128 + (((g * 4 + kq) ^ swz) << 3));
      short8 vf3 = *reinterpret_cast<const short8*>(vrow0 + 48 * 128 + (((g * 4 + kq) ^ swz) << 3));

      // ---- O += P.V
      oacc[0] = __builtin_amdgcn_mfma_f32_16x16x32_bf16(pa.s, vf0, oacc[0], 0, 0, 0);
      oacc[1] = __builtin_amdgcn_mfma_f32_16x16x32_bf16(pa.s, vf1, oacc[1], 0, 0, 0);
      oacc[2] = __builtin_amdgcn_mfma_f32_16x16x32_bf16(pa.s, vf2, oacc[2], 0, 0, 0);
      oacc[3] = __builtin_amdgcn_mfma_f32_16x16x32_bf16(pa.s, vf3, oacc[3], 0, 0, 0);
    }
    // one barrier per tile: staged loads landed (per-wave) + all reads done
    sfence();
    vmwait<0>();
    __builtin_amdgcn_s_barrier();
    sfence();
  }
#undef STAGE

  // ---- l: sum the 4 kq-copies; then fetch l[q=kq*4+r] from lane rr=q
  l_acc += __shfl_xor(l_acc, 16);
  l_acc += __shfl_xor(l_acc, 32);

  u16* aob = ao + ((size_t)(b * 256 + q0)) * 1024 + h * 64;
#pragma unroll
  for (int r = 0; r < 4; ++r) {
    float lv = __shfl(l_acc, kq * 4 + r);
    float inv = 1.0f / lv;
    int qrow_o = kq * 4 + r;
#pragma unroll
    for (int ni = 0; ni < 4; ++ni) {
      int d = ni * 16 + rr;
      aob[(size_t)qrow_o * 1024 + d] = f2bf(oacc[ni][r] * inv);
    }
  }
}

// ---- out-proj: 64x64 tiles, 512 blocks, 4 blocks/CU; bias+residual fused ----
__global__ __launch_bounds__(256, 4) void gemm_out(
    const u16* __restrict__ A, const u16* __restrict__ W,
    const float* __restrict__ bias, const float* __restrict__ resid,
    float* __restrict__ out) {
  __shared__ __attribute__((aligned(16))) u16 Alds[2 * 64 * 64];
  __shared__ __attribute__((aligned(16))) u16 Blds[2 * 64 * 64];
  const int mB = blockIdx.y * 64;
  const int nB = blockIdx.x * 64;
  const floatx4 zz = {0.f, 0.f, 0.f, 0.f};
  floatx4 acc[2][2] = {{zz, zz}, {zz, zz}};
  gemm_core<2, 2>(A + (size_t)mB * 1024, 1024, W + (size_t)nB * 1024, 1024, 1024,
                  Alds, Blds, acc);
  const int lane = threadIdx.x & 63, wave = threadIdx.x >> 6;
  const int rr = lane & 15, r4 = (lane >> 4) * 4;
  const int m0w = (wave & 1) * 32, n0w = (wave >> 1) * 32;
#pragma unroll
  for (int mi = 0; mi < 2; ++mi)
#pragma unroll
    for (int ni = 0; ni < 2; ++ni) {
      int n = nB + n0w + ni * 16 + rr;
      float bv = bias[n];
#pragma unroll
      for (int r = 0; r < 4; ++r) {
        int m = mB + m0w + mi * 16 + r4 + r;
        size_t idx = (size_t)m * 1024 + n;
        out[idx] = acc[mi][ni][r] + bv + resid[idx];
      }
    }
}

extern "C" void kernel_launch(void* const* d_in, const int* in_sizes, int n_in,
                              void* d_out, int out_size, void* d_ws, size_t ws_size,
                              hipStream_t stream) {
  const float* sources = (const float*)d_in[0];  // [8,2048,1024]
  const float* queries = (const float*)d_in[1];  // [8,256,1024]
  const float* w_in    = (const float*)d_in[2];  // [3072,1024]
  const float* b_in    = (const float*)d_in[3];  // [3072]
  const float* w_out   = (const float*)d_in[4];  // [1024,1024]
  const float* b_out   = (const float*)d_in[5];  // [1024]
  float* out = (float*)d_out;                    // [8,256,1024] fp32

  char* ws = (char*)d_ws;
  size_t off = 0;
  auto alloc = [&](size_t elems) -> u16* {
    u16* p = (u16*)(ws + off);
    off += elems * sizeof(u16);
    off = (off + 255) & ~(size_t)255;
    return p;
  };
  u16* s_bf  = alloc((size_t)16777216);  // sources bf16
  u16* qy_bf = alloc((size_t)2097152);   // queries bf16
  u16* wi_bf = alloc((size_t)3145728);   // w_in bf16
  u16* wo_bf = alloc((size_t)1048576);   // w_out bf16
  u16* qp    = alloc((size_t)2097152);   // projected q (pre-scaled 1/8)
  u16* kp    = alloc((size_t)16777216);  // projected k
  u16* vT    = alloc((size_t)16777216);  // projected v, [bh][d][n]
  u16* ao    = alloc((size_t)2097152);   // attention output

  // 1) casts
  f2bf_multi<<<dim3(22528), 256, 0, stream>>>(
      sources, s_bf, queries, qy_bf, w_in, wi_bf, w_out, wo_bf);

  // 2) projections (kv8 = 2 clean rounds; proj_q now 512 blocks @ 4/CU)
  gemm_proj_kv8<<<dim3(8, 64), 512, 0, stream>>>(s_bf, wi_bf, b_in, kp, vT);
  gemm_proj_q<<<dim3(16, 32), 256, 0, stream>>>(qy_bf, wi_bf, b_in, qp);

  // 3) fused attention v4 (LDS-staged K/V + in-register P, 1 barrier/tile)
  attn_fused<<<dim3(512), 256, 0, stream>>>(qp, kp, vT, ao);

  // 4) out-proj + bias + residual (512 blocks @ 4/CU)
  gemm_out<<<dim3(16, 32), 256, 0, stream>>>(ao, wo_bf, b_out, queries, out);
}